// Round 1
// baseline (1504.214 us; speedup 1.0000x reference)
//
#include <hip/hip_runtime.h>
#include <cstdint>
#include <cstddef>

// PatchAttention on MI355X — round 1: fp32 modular baseline.
// Pipeline: rpe_table -> im2col -> GEMM(embed) -> GEMM(qkv) -> flash-attn
//           -> GEMM(proj) -> GEMM(unembed cols) -> col2im(+bias).
// All fp32, VALU-bound by design; establishes correctness + counters before
// moving the big GEMMs to bf16 MFMA.

__device__ __forceinline__ float dot4f(float4 a, float4 b) {
  return a.x * b.x + a.y * b.y + a.z * b.z + a.w * b.w;
}

// ---------------------------------------------------------------------------
// RPE table: MLP(2 -> 512 -> 8) over the 63x63 relative-coordinate grid.
__global__ __launch_bounds__(256) void rpe_table_kernel(
    const float* __restrict__ w1, const float* __restrict__ b1,
    const float* __restrict__ w2, float* __restrict__ table) {
  int t = blockIdx.x * 256 + threadIdx.x;
  if (t >= 3969) return;
  int a = t / 63, c = t - a * 63;
  float rh = (float)(a - 31) * (1.0f / 31.0f);
  float rw = (float)(c - 31) * (1.0f / 31.0f);
  float acc[8];
#pragma unroll
  for (int h = 0; h < 8; h++) acc[h] = 0.f;
  for (int j = 0; j < 512; j++) {
    float hv = fmaxf(rh * w1[2 * j] + rw * w1[2 * j + 1] + b1[j], 0.f);
#pragma unroll
    for (int h = 0; h < 8; h++) acc[h] += hv * w2[h * 512 + j];
  }
#pragma unroll
  for (int h = 0; h < 8; h++) table[t * 8 + h] = acc[h];
}

// ---------------------------------------------------------------------------
// im2col: x [8,256,128,128] -> A [8192 tokens, 4096 = (c,p,q)]
// thread = (c, bn); reads coalesced along w, writes one full 64B line.
__global__ __launch_bounds__(256) void im2col_kernel(
    const float* __restrict__ x, float* __restrict__ A) {
  int gid = blockIdx.x * 256 + threadIdx.x;  // 2,097,152
  int bn = gid & 8191;
  int c = gid >> 13;
  int b = bn >> 10;
  int hw = bn & 1023;
  int h = hw >> 5, w = hw & 31;
  const float4* x4 = (const float4*)x;
  float4* A4 = (float4*)(A + (size_t)bn * 4096 + c * 16);
  int base = ((b * 256 + c) * 128 + 4 * h) * 32 + w;  // float4 index
#pragma unroll
  for (int p = 0; p < 4; p++) A4[p] = x4[base + p * 32];
}

// col2im: Ycol [8192, 4096=(o,p,q)] + bias[o] -> y [8,256,128,128]
__global__ __launch_bounds__(256) void col2im_kernel(
    const float* __restrict__ Ycol, const float* __restrict__ bun,
    float* __restrict__ y) {
  int gid = blockIdx.x * 256 + threadIdx.x;
  int bn = gid & 8191;
  int o = gid >> 13;
  int b = bn >> 10;
  int hw = bn & 1023;
  int h = hw >> 5, w = hw & 31;
  float bo = bun[o];
  const float4* Y4 = (const float4*)(Ycol + (size_t)bn * 4096 + o * 16);
  float4* y4 = (float4*)y;
  int base = ((b * 256 + o) * 128 + 4 * h) * 32 + w;
#pragma unroll
  for (int p = 0; p < 4; p++) {
    float4 v = Y4[p];
    v.x += bo; v.y += bo; v.z += bo; v.w += bo;
    y4[base + p * 32] = v;
  }
}

// ---------------------------------------------------------------------------
// fp32 GEMM: C[M,Nc] = A[M,K] * B (+bias per col).
// BT=1: B given as [Nc,K] row-major (i.e. we multiply by B^T), ldb = K.
// BT=0: B given as [K,Nc] row-major, ldb = Nc.
// 128x128 tile, BK=16, 256 threads, 8x8 micro-tile.
template <int BT>
__global__ __launch_bounds__(256) void gemm_kernel(
    const float* __restrict__ A, const float* __restrict__ Bm,
    const float* __restrict__ bias, float* __restrict__ C,
    int M, int Nc, int K, int lda, int ldb, int ldc) {
  __shared__ float As[16][132];
  __shared__ float Bs[16][132];
  int tid = threadIdx.x;
  int n0 = blockIdx.x * 128;
  int m0 = blockIdx.y * 128;
  int tx = tid & 15, ty = tid >> 4;
  float acc[8][8];
#pragma unroll
  for (int i = 0; i < 8; i++)
#pragma unroll
    for (int j = 0; j < 8; j++) acc[i][j] = 0.f;

  for (int k0 = 0; k0 < K; k0 += 16) {
#pragma unroll
    for (int t = 0; t < 2; t++) {
      int fi = tid + t * 256;
      int row = fi >> 2, q = fi & 3;
      float4 v = *(const float4*)(A + (size_t)(m0 + row) * lda + k0 + q * 4);
      As[q * 4 + 0][row] = v.x; As[q * 4 + 1][row] = v.y;
      As[q * 4 + 2][row] = v.z; As[q * 4 + 3][row] = v.w;
    }
    if (BT) {
#pragma unroll
      for (int t = 0; t < 2; t++) {
        int fi = tid + t * 256;
        int col = fi >> 2, q = fi & 3;
        float4 v = *(const float4*)(Bm + (size_t)(n0 + col) * ldb + k0 + q * 4);
        Bs[q * 4 + 0][col] = v.x; Bs[q * 4 + 1][col] = v.y;
        Bs[q * 4 + 2][col] = v.z; Bs[q * 4 + 3][col] = v.w;
      }
    } else {
#pragma unroll
      for (int t = 0; t < 2; t++) {
        int fi = tid + t * 256;
        int kk = fi >> 5, c4 = fi & 31;
        float4 v = *(const float4*)(Bm + (size_t)(k0 + kk) * ldb + n0 + c4 * 4);
        *(float4*)(&Bs[kk][c4 * 4]) = v;
      }
    }
    __syncthreads();
#pragma unroll
    for (int kk = 0; kk < 16; kk++) {
      float4 a0 = *(const float4*)(&As[kk][ty * 8]);
      float4 a1 = *(const float4*)(&As[kk][ty * 8 + 4]);
      float4 b0 = *(const float4*)(&Bs[kk][tx * 8]);
      float4 b1 = *(const float4*)(&Bs[kk][tx * 8 + 4]);
      float av[8] = {a0.x, a0.y, a0.z, a0.w, a1.x, a1.y, a1.z, a1.w};
      float bv[8] = {b0.x, b0.y, b0.z, b0.w, b1.x, b1.y, b1.z, b1.w};
#pragma unroll
      for (int i = 0; i < 8; i++)
#pragma unroll
        for (int j = 0; j < 8; j++) acc[i][j] += av[i] * bv[j];
    }
    __syncthreads();
  }
  float bv[8];
#pragma unroll
  for (int j = 0; j < 8; j++) bv[j] = bias ? bias[n0 + tx * 8 + j] : 0.f;
#pragma unroll
  for (int i = 0; i < 8; i++) {
    float* cp = C + (size_t)(m0 + ty * 8 + i) * ldc + n0 + tx * 8;
    float4 v0 = make_float4(acc[i][0] + bv[0], acc[i][1] + bv[1],
                            acc[i][2] + bv[2], acc[i][3] + bv[3]);
    float4 v1 = make_float4(acc[i][4] + bv[4], acc[i][5] + bv[5],
                            acc[i][6] + bv[6], acc[i][7] + bv[7]);
    *(float4*)cp = v0;
    *(float4*)(cp + 4) = v1;
  }
}

// ---------------------------------------------------------------------------
// Flash attention: one block = (b, h, 64-row Q tile). K/V tiles of 64.
// qkv layout [8192, 768] = [bn][which*256 + h*32 + d]. Bias gathered from
// the 3969x8 table on the fly. out = [8192, 256] token-major.
__global__ __launch_bounds__(256) void attn_kernel(
    const float* __restrict__ qkv, const float* __restrict__ table,
    float* __restrict__ out) {
  __shared__ float Qs[64][36];
  __shared__ float Ks[64][36];
  __shared__ float Vs[64][36];
  __shared__ float Ps[64][68];
  __shared__ float alpha_s[64];
  __shared__ float l_s[64];
  int tid = threadIdx.x;
  int blk = blockIdx.x;
  int qt = blk & 15;
  int bh = blk >> 4;
  int b = bh >> 3, h = bh & 7;
  int n0 = qt * 64;
  const float scale = 0.17677669529663687f;  // 1/sqrt(32)

#pragma unroll
  for (int t = 0; t < 2; t++) {
    int fi = tid + t * 256;
    int row = fi >> 3, d4 = fi & 7;
    float4 v = *(const float4*)(qkv + (size_t)(b * 1024 + n0 + row) * 768 +
                                h * 32 + d4 * 4);
    v.x *= scale; v.y *= scale; v.z *= scale; v.w *= scale;
    *(float4*)(&Qs[row][d4 * 4]) = v;
  }
  int cg = tid & 15, rg = tid >> 4;  // S phase: rows rg*4+i, cols cg*4+j
  int dq = tid & 7, rv = tid >> 3;   // PV phase: rows rv*2+r, dims dq*4+d
  float m_run[4], l_run[4];
  float O[2][4];
#pragma unroll
  for (int i = 0; i < 4; i++) { m_run[i] = -1e30f; l_run[i] = 0.f; }
#pragma unroll
  for (int r = 0; r < 2; r++)
#pragma unroll
    for (int d = 0; d < 4; d++) O[r][d] = 0.f;
  int qh[4], qw[4];
#pragma unroll
  for (int i = 0; i < 4; i++) {
    int qr = n0 + rg * 4 + i;
    qh[i] = qr >> 5; qw[i] = qr & 31;
  }

  for (int kt = 0; kt < 16; kt++) {
    __syncthreads();  // protect Ks/Vs/Ps/alpha_s reuse
    int k0 = kt * 64;
#pragma unroll
    for (int t = 0; t < 2; t++) {
      int fi = tid + t * 256;
      int row = fi >> 3, d4 = fi & 7;
      size_t base = (size_t)(b * 1024 + k0 + row) * 768 + h * 32 + d4 * 4;
      *(float4*)(&Ks[row][d4 * 4]) = *(const float4*)(qkv + base + 256);
      *(float4*)(&Vs[row][d4 * 4]) = *(const float4*)(qkv + base + 512);
    }
    __syncthreads();

    float s[4][4];
#pragma unroll
    for (int i = 0; i < 4; i++)
#pragma unroll
      for (int j = 0; j < 4; j++) s[i][j] = 0.f;
#pragma unroll
    for (int d4 = 0; d4 < 8; d4++) {
      float4 aq[4], bk[4];
#pragma unroll
      for (int i = 0; i < 4; i++) aq[i] = *(const float4*)(&Qs[rg * 4 + i][d4 * 4]);
#pragma unroll
      for (int j = 0; j < 4; j++) bk[j] = *(const float4*)(&Ks[cg * 4 + j][d4 * 4]);
#pragma unroll
      for (int i = 0; i < 4; i++)
#pragma unroll
        for (int j = 0; j < 4; j++) s[i][j] += dot4f(aq[i], bk[j]);
    }
    // dynamic RPE bias gather
#pragma unroll
    for (int j = 0; j < 4; j++) {
      int kc = k0 + cg * 4 + j;
      int kh = kc >> 5, kw = kc & 31;
#pragma unroll
      for (int i = 0; i < 4; i++) {
        int idx = (qh[i] - kh + 31) * 63 + (qw[i] - kw + 31);
        s[i][j] += table[idx * 8 + h];
      }
    }
    // online softmax (reduce across the 16 cg lanes; low 4 bits of lane)
#pragma unroll
    for (int i = 0; i < 4; i++) {
      float mx = fmaxf(fmaxf(s[i][0], s[i][1]), fmaxf(s[i][2], s[i][3]));
#pragma unroll
      for (int off = 1; off < 16; off <<= 1) mx = fmaxf(mx, __shfl_xor(mx, off, 64));
      float m_new = fmaxf(m_run[i], mx);
      float p0 = __expf(s[i][0] - m_new);
      float p1 = __expf(s[i][1] - m_new);
      float p2 = __expf(s[i][2] - m_new);
      float p3 = __expf(s[i][3] - m_new);
      float sum = p0 + p1 + p2 + p3;
#pragma unroll
      for (int off = 1; off < 16; off <<= 1) sum += __shfl_xor(sum, off, 64);
      float alpha = __expf(m_run[i] - m_new);
      l_run[i] = l_run[i] * alpha + sum;
      m_run[i] = m_new;
      *(float4*)(&Ps[rg * 4 + i][cg * 4]) = make_float4(p0, p1, p2, p3);
      if (cg == 0) {
        alpha_s[rg * 4 + i] = alpha;
        if (kt == 15) l_s[rg * 4 + i] = l_run[i];
      }
    }
    __syncthreads();
    // PV accumulate
    float a0 = alpha_s[rv * 2], a1 = alpha_s[rv * 2 + 1];
#pragma unroll
    for (int d = 0; d < 4; d++) { O[0][d] *= a0; O[1][d] *= a1; }
#pragma unroll
    for (int k4 = 0; k4 < 16; k4++) {
      float4 p0 = *(const float4*)(&Ps[rv * 2][k4 * 4]);
      float4 p1 = *(const float4*)(&Ps[rv * 2 + 1][k4 * 4]);
      float4 v0 = *(const float4*)(&Vs[k4 * 4 + 0][dq * 4]);
      float4 v1 = *(const float4*)(&Vs[k4 * 4 + 1][dq * 4]);
      float4 v2 = *(const float4*)(&Vs[k4 * 4 + 2][dq * 4]);
      float4 v3 = *(const float4*)(&Vs[k4 * 4 + 3][dq * 4]);
      O[0][0] += p0.x * v0.x + p0.y * v1.x + p0.z * v2.x + p0.w * v3.x;
      O[0][1] += p0.x * v0.y + p0.y * v1.y + p0.z * v2.y + p0.w * v3.y;
      O[0][2] += p0.x * v0.z + p0.y * v1.z + p0.z * v2.z + p0.w * v3.z;
      O[0][3] += p0.x * v0.w + p0.y * v1.w + p0.z * v2.w + p0.w * v3.w;
      O[1][0] += p1.x * v0.x + p1.y * v1.x + p1.z * v2.x + p1.w * v3.x;
      O[1][1] += p1.x * v0.y + p1.y * v1.y + p1.z * v2.y + p1.w * v3.y;
      O[1][2] += p1.x * v0.z + p1.y * v1.z + p1.z * v2.z + p1.w * v3.z;
      O[1][3] += p1.x * v0.w + p1.y * v1.w + p1.z * v2.w + p1.w * v3.w;
    }
  }
  float inv0 = 1.0f / l_s[rv * 2];
  float inv1 = 1.0f / l_s[rv * 2 + 1];
  float4 o0 = make_float4(O[0][0] * inv0, O[0][1] * inv0, O[0][2] * inv0, O[0][3] * inv0);
  float4 o1 = make_float4(O[1][0] * inv1, O[1][1] * inv1, O[1][2] * inv1, O[1][3] * inv1);
  *(float4*)(out + (size_t)(b * 1024 + n0 + rv * 2) * 256 + h * 32 + dq * 4) = o0;
  *(float4*)(out + (size_t)(b * 1024 + n0 + rv * 2 + 1) * 256 + h * 32 + dq * 4) = o1;
}

// ---------------------------------------------------------------------------
extern "C" void kernel_launch(void* const* d_in, const int* in_sizes, int n_in,
                              void* d_out, int out_size, void* d_ws, size_t ws_size,
                              hipStream_t stream) {
  const float* x         = (const float*)d_in[0];
  const float* w_embed   = (const float*)d_in[1];
  const float* b_embed   = (const float*)d_in[2];
  const float* cpb_w1    = (const float*)d_in[3];
  const float* cpb_b1    = (const float*)d_in[4];
  const float* cpb_w2    = (const float*)d_in[5];
  const float* w_qkv     = (const float*)d_in[6];
  const float* b_qkv     = (const float*)d_in[7];
  const float* w_proj    = (const float*)d_in[8];
  const float* b_proj    = (const float*)d_in[9];
  const float* w_unembed = (const float*)d_in[10];
  const float* b_unembed = (const float*)d_in[11];
  float* out = (float*)d_out;

  // workspace layout (floats): Abig is reused as Ycol after GEMM1 consumes it.
  float* ws     = (float*)d_ws;
  float* Abig   = ws;                   // 33,554,432  (im2col A / unembed Ycol)
  float* tok    = Abig + 33554432;      //  2,097,152
  float* qkv    = tok + 2097152;        //  6,291,456
  float* attn_o = qkv + 6291456;        //  2,097,152
  float* z2     = attn_o + 2097152;     //  2,097,152
  float* table  = z2 + 2097152;         //     32,768
  // total: 46,170,112 floats = 184.7 MB

  rpe_table_kernel<<<16, 256, 0, stream>>>(cpb_w1, cpb_b1, cpb_w2, table);
  im2col_kernel<<<8192, 256, 0, stream>>>(x, Abig);
  // embed: tok[8192,256] = A[8192,4096] @ w_embed^T + b_embed
  gemm_kernel<1><<<dim3(2, 64), 256, 0, stream>>>(
      Abig, w_embed, b_embed, tok, 8192, 256, 4096, 4096, 4096, 256);
  // qkv: [8192,768] = tok @ w_qkv^T + b_qkv
  gemm_kernel<1><<<dim3(6, 64), 256, 0, stream>>>(
      tok, w_qkv, b_qkv, qkv, 8192, 768, 256, 256, 256, 768);
  attn_kernel<<<1024, 256, 0, stream>>>(qkv, table, attn_o);
  // proj: z2[8192,256] = attn_o @ w_proj^T + b_proj
  gemm_kernel<1><<<dim3(2, 64), 256, 0, stream>>>(
      attn_o, w_proj, b_proj, z2, 8192, 256, 256, 256, 256, 256);
  // unembed cols: Ycol[8192,4096] = z2 @ w_unembed[256,4096]
  gemm_kernel<0><<<dim3(32, 64), 256, 0, stream>>>(
      z2, w_unembed, nullptr, Abig, 8192, 4096, 256, 256, 4096, 4096);
  col2im_kernel<<<8192, 256, 0, stream>>>(Abig, b_unembed, out);
}

// Round 2
// 852.347 us; speedup vs baseline: 1.7648x; 1.7648x over previous
//
#include <hip/hip_runtime.h>
#include <cstdint>
#include <cstddef>

// PatchAttention on MI355X — round 2: bf16 MFMA GEMMs (m97 recipe),
// fused col2im epilogue, fp32 flash attention (unchanged math).

typedef __bf16 bf16x8 __attribute__((ext_vector_type(8)));
typedef float f32x4 __attribute__((ext_vector_type(4)));
typedef unsigned short u16x4 __attribute__((ext_vector_type(4)));

__device__ __forceinline__ unsigned short f2bf(float f) {
  unsigned u = __builtin_bit_cast(unsigned, f);
  u += 0x7fffu + ((u >> 16) & 1u);  // round-to-nearest-even
  return (unsigned short)(u >> 16);
}

__device__ __forceinline__ float dot4f(float4 a, float4 b) {
  return a.x * b.x + a.y * b.y + a.z * b.z + a.w * b.w;
}

// async 16B global -> LDS (wave-uniform base + lane*16 layout)
__device__ __forceinline__ void async_ld16(const void* g, void* l) {
  __builtin_amdgcn_global_load_lds(
      (const __attribute__((address_space(1))) void*)g,
      (__attribute__((address_space(3))) void*)l, 16, 0, 0);
}

// ---------------------------------------------------------------------------
// RPE table: MLP(2 -> 512 -> 8) over the 63x63 relative-coordinate grid.
__global__ __launch_bounds__(256) void rpe_table_kernel(
    const float* __restrict__ w1, const float* __restrict__ b1,
    const float* __restrict__ w2, float* __restrict__ table) {
  int t = blockIdx.x * 256 + threadIdx.x;
  if (t >= 3969) return;
  int a = t / 63, c = t - a * 63;
  float rh = (float)(a - 31) * (1.0f / 31.0f);
  float rw = (float)(c - 31) * (1.0f / 31.0f);
  float acc[8];
#pragma unroll
  for (int h = 0; h < 8; h++) acc[h] = 0.f;
  for (int j = 0; j < 512; j++) {
    float hv = fmaxf(rh * w1[2 * j] + rw * w1[2 * j + 1] + b1[j], 0.f);
#pragma unroll
    for (int h = 0; h < 8; h++) acc[h] += hv * w2[h * 512 + j];
  }
#pragma unroll
  for (int h = 0; h < 8; h++) table[t * 8 + h] = acc[h];
}

// ---------------------------------------------------------------------------
// generic fp32 -> bf16 convert, 8 elems/thread
__global__ __launch_bounds__(256) void cvt_bf16_kernel(
    const float* __restrict__ src, unsigned short* __restrict__ dst, int n8) {
  int i = blockIdx.x * 256 + threadIdx.x;
  if (i >= n8) return;
  const float4* s4 = (const float4*)src + (size_t)i * 2;
  float4 a = s4[0], b = s4[1];
  unsigned short t[8] = {f2bf(a.x), f2bf(a.y), f2bf(a.z), f2bf(a.w),
                         f2bf(b.x), f2bf(b.y), f2bf(b.z), f2bf(b.w)};
  *(uint4*)(dst + (size_t)i * 8) = *(const uint4*)t;
}

// transpose+convert: src [256][4096] f32 -> dst [4096][256] bf16
__global__ __launch_bounds__(256) void transpose_cvt_kernel(
    const float* __restrict__ src, unsigned short* __restrict__ dst) {
  __shared__ float tile[32][33];
  int bx = blockIdx.x;  // along 4096
  int by = blockIdx.y;  // along 256
  int tx = threadIdx.x & 31, ty = threadIdx.x >> 5;
#pragma unroll
  for (int r = 0; r < 32; r += 8)
    tile[ty + r][tx] = src[(size_t)(by * 32 + ty + r) * 4096 + bx * 32 + tx];
  __syncthreads();
#pragma unroll
  for (int r = 0; r < 32; r += 8)
    dst[(size_t)(bx * 32 + ty + r) * 256 + by * 32 + tx] = f2bf(tile[tx][ty + r]);
}

// ---------------------------------------------------------------------------
// im2col: x [8,256,128,128] f32 -> A [8192, 4096=(c,p,q)] bf16
__global__ __launch_bounds__(256) void im2col_bf16_kernel(
    const float* __restrict__ x, unsigned short* __restrict__ A) {
  int gid = blockIdx.x * 256 + threadIdx.x;  // 2,097,152
  int bn = gid & 8191;
  int c = gid >> 13;
  int b = bn >> 10;
  int hw = bn & 1023;
  int h = hw >> 5, w = hw & 31;
  const float4* x4 = (const float4*)x;
  int base = ((b * 256 + c) * 128 + 4 * h) * 32 + w;  // float4 index
  unsigned short t[16];
#pragma unroll
  for (int p = 0; p < 4; p++) {
    float4 v = x4[base + p * 32];
    t[p * 4 + 0] = f2bf(v.x); t[p * 4 + 1] = f2bf(v.y);
    t[p * 4 + 2] = f2bf(v.z); t[p * 4 + 3] = f2bf(v.w);
  }
  unsigned short* dst = A + (size_t)bn * 4096 + c * 16;
  *(uint4*)dst = *(const uint4*)t;
  *(uint4*)(dst + 8) = *(const uint4*)(t + 8);
}

// ---------------------------------------------------------------------------
// bf16 MFMA GEMM: C[M,N] = A[M,K] * B^T (B given [N,K] bf16) + bias.
// 128x128 tile, BK=32, 256 threads (4 waves, 2x2 of 64x64), m97 staging.
// CMODE: 0 = fp32 C, 1 = bf16 C, 2 = fused col2im into y[8,256,128,128] f32.
template <int CMODE>
__global__ __launch_bounds__(256) void gemm_mfma_kernel(
    const unsigned short* __restrict__ A, const unsigned short* __restrict__ B,
    const float* __restrict__ bias, void* __restrict__ Cv,
    int M, int N, int K, int lda, int ldb, int ldc) {
  __shared__ unsigned short As[128 * 32];
  __shared__ unsigned short Bs[128 * 32];
  int tid = threadIdx.x;
  int lane = tid & 63;
  int wave = tid >> 6;
  int m0 = blockIdx.y * 128, n0 = blockIdx.x * 128;
  int wm = (wave & 1) * 64, wn = (wave >> 1) * 64;

  f32x4 acc[4][4];
#pragma unroll
  for (int i = 0; i < 4; i++)
#pragma unroll
    for (int j = 0; j < 4; j++) acc[i][j] = (f32x4){0.f, 0.f, 0.f, 0.f};

  // staging: flat chunk f covers row f>>2, k-offset (f&3)*8; LDS byte f*16
  int f0 = tid, f1 = tid + 256;
  const unsigned short* Ag0 = A + (size_t)(m0 + (f0 >> 2)) * lda + (f0 & 3) * 8;
  const unsigned short* Ag1 = A + (size_t)(m0 + (f1 >> 2)) * lda + (f1 & 3) * 8;
  const unsigned short* Bg0 = B + (size_t)(n0 + (f0 >> 2)) * ldb + (f0 & 3) * 8;
  const unsigned short* Bg1 = B + (size_t)(n0 + (f1 >> 2)) * ldb + (f1 & 3) * 8;
  unsigned short* Al0 = As + f0 * 8;
  unsigned short* Al1 = As + f1 * 8;
  unsigned short* Bl0 = Bs + f0 * 8;
  unsigned short* Bl1 = Bs + f1 * 8;

  int fr = lane & 15;   // row/col within 16-tile
  int fh = lane >> 4;   // k-chunk 0..3 (8 bf16 each)

  for (int k0 = 0; k0 < K; k0 += 32) {
    __syncthreads();  // all waves done reading previous tile
    async_ld16(Ag0 + k0, Al0);
    async_ld16(Ag1 + k0, Al1);
    async_ld16(Bg0 + k0, Bl0);
    async_ld16(Bg1 + k0, Bl1);
    __syncthreads();  // vmcnt(0) drained before barrier -> staging visible

    bf16x8 af[4], bf[4];
#pragma unroll
    for (int t = 0; t < 4; t++) {
      af[t] = *(const bf16x8*)(As + (wm + t * 16 + fr) * 32 + fh * 8);
      bf[t] = *(const bf16x8*)(Bs + (wn + t * 16 + fr) * 32 + fh * 8);
    }
#pragma unroll
    for (int mt = 0; mt < 4; mt++)
#pragma unroll
      for (int nt = 0; nt < 4; nt++)
        acc[mt][nt] = __builtin_amdgcn_mfma_f32_16x16x32_bf16(
            af[mt], bf[nt], acc[mt][nt], 0, 0, 0);
  }

  // epilogue: C/D layout col = lane&15, row = (lane>>4)*4 + reg
#pragma unroll
  for (int mt = 0; mt < 4; mt++) {
    int row0 = m0 + wm + mt * 16 + fh * 4;  // rows row0..row0+3 (aligned 4)
    if (CMODE == 2) {
      // row -> token bn: b = row>>10, hp = (row>>5)&31, wp = row&31
      int b = row0 >> 10, hp = (row0 >> 5) & 31, wp = row0 & 31;
      size_t rowoff0 = (size_t)b * 4194304 + hp * 512 + wp * 4;  // dwords
      float* y = (float*)Cv;
#pragma unroll
      for (int nt = 0; nt < 4; nt++) {
        int col = n0 + wn + nt * 16 + fr;
        int o = col >> 4, p = (col >> 2) & 3, q = col & 3;
        size_t coloff = (size_t)o * 16384 + p * 128 + q;
        float bv = bias[o];
#pragma unroll
        for (int r = 0; r < 4; r++)
          y[rowoff0 + r * 4 + coloff] = acc[mt][nt][r] + bv;
      }
    } else {
#pragma unroll
      for (int nt = 0; nt < 4; nt++) {
        int col = n0 + wn + nt * 16 + fr;
        float bv = bias ? bias[col] : 0.f;
        if (CMODE == 0) {
          float* C = (float*)Cv;
#pragma unroll
          for (int r = 0; r < 4; r++)
            C[(size_t)(row0 + r) * ldc + col] = acc[mt][nt][r] + bv;
        } else {
          unsigned short* C = (unsigned short*)Cv;
#pragma unroll
          for (int r = 0; r < 4; r++)
            C[(size_t)(row0 + r) * ldc + col] = f2bf(acc[mt][nt][r] + bv);
        }
      }
    }
  }
}

// ---------------------------------------------------------------------------
// Flash attention (fp32 math, bf16 output): one block = (b, h, 64-row Q tile).
__global__ __launch_bounds__(256) void attn_kernel(
    const float* __restrict__ qkv, const float* __restrict__ table,
    unsigned short* __restrict__ out) {
  __shared__ float Qs[64][36];
  __shared__ float Ks[64][36];
  __shared__ float Vs[64][36];
  __shared__ float Ps[64][68];
  __shared__ float alpha_s[64];
  __shared__ float l_s[64];
  int tid = threadIdx.x;
  int blk = blockIdx.x;
  int qt = blk & 15;
  int bh = blk >> 4;
  int b = bh >> 3, h = bh & 7;
  int n0 = qt * 64;
  const float scale = 0.17677669529663687f;  // 1/sqrt(32)

#pragma unroll
  for (int t = 0; t < 2; t++) {
    int fi = tid + t * 256;
    int row = fi >> 3, d4 = fi & 7;
    float4 v = *(const float4*)(qkv + (size_t)(b * 1024 + n0 + row) * 768 +
                                h * 32 + d4 * 4);
    v.x *= scale; v.y *= scale; v.z *= scale; v.w *= scale;
    *(float4*)(&Qs[row][d4 * 4]) = v;
  }
  int cg = tid & 15, rg = tid >> 4;  // S phase
  int dq = tid & 7, rv = tid >> 3;   // PV phase
  float m_run[4], l_run[4];
  float O[2][4];
#pragma unroll
  for (int i = 0; i < 4; i++) { m_run[i] = -1e30f; l_run[i] = 0.f; }
#pragma unroll
  for (int r = 0; r < 2; r++)
#pragma unroll
    for (int d = 0; d < 4; d++) O[r][d] = 0.f;
  int qh[4], qw[4];
#pragma unroll
  for (int i = 0; i < 4; i++) {
    int qr = n0 + rg * 4 + i;
    qh[i] = qr >> 5; qw[i] = qr & 31;
  }

  for (int kt = 0; kt < 16; kt++) {
    __syncthreads();
    int k0 = kt * 64;
#pragma unroll
    for (int t = 0; t < 2; t++) {
      int fi = tid + t * 256;
      int row = fi >> 3, d4 = fi & 7;
      size_t base = (size_t)(b * 1024 + k0 + row) * 768 + h * 32 + d4 * 4;
      *(float4*)(&Ks[row][d4 * 4]) = *(const float4*)(qkv + base + 256);
      *(float4*)(&Vs[row][d4 * 4]) = *(const float4*)(qkv + base + 512);
    }
    __syncthreads();

    float s[4][4];
#pragma unroll
    for (int i = 0; i < 4; i++)
#pragma unroll
      for (int j = 0; j < 4; j++) s[i][j] = 0.f;
#pragma unroll
    for (int d4 = 0; d4 < 8; d4++) {
      float4 aq[4], bk[4];
#pragma unroll
      for (int i = 0; i < 4; i++) aq[i] = *(const float4*)(&Qs[rg * 4 + i][d4 * 4]);
#pragma unroll
      for (int j = 0; j < 4; j++) bk[j] = *(const float4*)(&Ks[cg * 4 + j][d4 * 4]);
#pragma unroll
      for (int i = 0; i < 4; i++)
#pragma unroll
        for (int j = 0; j < 4; j++) s[i][j] += dot4f(aq[i], bk[j]);
    }
#pragma unroll
    for (int j = 0; j < 4; j++) {
      int kc = k0 + cg * 4 + j;
      int kh = kc >> 5, kw = kc & 31;
#pragma unroll
      for (int i = 0; i < 4; i++) {
        int idx = (qh[i] - kh + 31) * 63 + (qw[i] - kw + 31);
        s[i][j] += table[idx * 8 + h];
      }
    }
#pragma unroll
    for (int i = 0; i < 4; i++) {
      float mx = fmaxf(fmaxf(s[i][0], s[i][1]), fmaxf(s[i][2], s[i][3]));
#pragma unroll
      for (int off = 1; off < 16; off <<= 1) mx = fmaxf(mx, __shfl_xor(mx, off, 64));
      float m_new = fmaxf(m_run[i], mx);
      float p0 = __expf(s[i][0] - m_new);
      float p1 = __expf(s[i][1] - m_new);
      float p2 = __expf(s[i][2] - m_new);
      float p3 = __expf(s[i][3] - m_new);
      float sum = p0 + p1 + p2 + p3;
#pragma unroll
      for (int off = 1; off < 16; off <<= 1) sum += __shfl_xor(sum, off, 64);
      float alpha = __expf(m_run[i] - m_new);
      l_run[i] = l_run[i] * alpha + sum;
      m_run[i] = m_new;
      *(float4*)(&Ps[rg * 4 + i][cg * 4]) = make_float4(p0, p1, p2, p3);
      if (cg == 0) {
        alpha_s[rg * 4 + i] = alpha;
        if (kt == 15) l_s[rg * 4 + i] = l_run[i];
      }
    }
    __syncthreads();
    float a0 = alpha_s[rv * 2], a1 = alpha_s[rv * 2 + 1];
#pragma unroll
    for (int d = 0; d < 4; d++) { O[0][d] *= a0; O[1][d] *= a1; }
#pragma unroll
    for (int k4 = 0; k4 < 16; k4++) {
      float4 p0 = *(const float4*)(&Ps[rv * 2][k4 * 4]);
      float4 p1 = *(const float4*)(&Ps[rv * 2 + 1][k4 * 4]);
      float4 v0 = *(const float4*)(&Vs[k4 * 4 + 0][dq * 4]);
      float4 v1 = *(const float4*)(&Vs[k4 * 4 + 1][dq * 4]);
      float4 v2 = *(const float4*)(&Vs[k4 * 4 + 2][dq * 4]);
      float4 v3 = *(const float4*)(&Vs[k4 * 4 + 3][dq * 4]);
      O[0][0] += p0.x * v0.x + p0.y * v1.x + p0.z * v2.x + p0.w * v3.x;
      O[0][1] += p0.x * v0.y + p0.y * v1.y + p0.z * v2.y + p0.w * v3.y;
      O[0][2] += p0.x * v0.z + p0.y * v1.z + p0.z * v2.z + p0.w * v3.z;
      O[0][3] += p0.x * v0.w + p0.y * v1.w + p0.z * v2.w + p0.w * v3.w;
      O[1][0] += p1.x * v0.x + p1.y * v1.x + p1.z * v2.x + p1.w * v3.x;
      O[1][1] += p1.x * v0.y + p1.y * v1.y + p1.z * v2.y + p1.w * v3.y;
      O[1][2] += p1.x * v0.z + p1.y * v1.z + p1.z * v2.z + p1.w * v3.z;
      O[1][3] += p1.x * v0.w + p1.y * v1.w + p1.z * v2.w + p1.w * v3.w;
    }
  }
  float inv0 = 1.0f / l_s[rv * 2];
  float inv1 = 1.0f / l_s[rv * 2 + 1];
  u16x4 o0 = {f2bf(O[0][0] * inv0), f2bf(O[0][1] * inv0),
              f2bf(O[0][2] * inv0), f2bf(O[0][3] * inv0)};
  u16x4 o1 = {f2bf(O[1][0] * inv1), f2bf(O[1][1] * inv1),
              f2bf(O[1][2] * inv1), f2bf(O[1][3] * inv1)};
  *(u16x4*)(out + (size_t)(b * 1024 + n0 + rv * 2) * 256 + h * 32 + dq * 4) = o0;
  *(u16x4*)(out + (size_t)(b * 1024 + n0 + rv * 2 + 1) * 256 + h * 32 + dq * 4) = o1;
}

// ---------------------------------------------------------------------------
extern "C" void kernel_launch(void* const* d_in, const int* in_sizes, int n_in,
                              void* d_out, int out_size, void* d_ws, size_t ws_size,
                              hipStream_t stream) {
  const float* x         = (const float*)d_in[0];
  const float* w_embed   = (const float*)d_in[1];
  const float* b_embed   = (const float*)d_in[2];
  const float* cpb_w1    = (const float*)d_in[3];
  const float* cpb_b1    = (const float*)d_in[4];
  const float* cpb_w2    = (const float*)d_in[5];
  const float* w_qkv     = (const float*)d_in[6];
  const float* b_qkv     = (const float*)d_in[7];
  const float* w_proj    = (const float*)d_in[8];
  const float* b_proj    = (const float*)d_in[9];
  const float* w_unembed = (const float*)d_in[10];
  const float* b_unembed = (const float*)d_in[11];
  float* out = (float*)d_out;

  // workspace layout (~105 MB)
  char* w = (char*)d_ws;
  unsigned short* Abig  = (unsigned short*)w; w += (size_t)8192 * 4096 * 2;  // 64 MB
  unsigned short* tok   = (unsigned short*)w; w += (size_t)8192 * 256 * 2;   //  4 MB
  float*          qkvb  = (float*)w;          w += (size_t)8192 * 768 * 4;   // 24 MB
  unsigned short* attno = (unsigned short*)w; w += (size_t)8192 * 256 * 2;   //  4 MB
  unsigned short* z2    = (unsigned short*)w; w += (size_t)8192 * 256 * 2;   //  4 MB
  float*          table = (float*)w;          w += (size_t)32768 * 4;        // 128 KB
  unsigned short* wE    = (unsigned short*)w; w += (size_t)1048576 * 2;      //  2 MB
  unsigned short* wQ    = (unsigned short*)w; w += (size_t)196608 * 2;       // 384 KB
  unsigned short* wP    = (unsigned short*)w; w += (size_t)65536 * 2;        // 128 KB
  unsigned short* wUt   = (unsigned short*)w; w += (size_t)1048576 * 2;      //  2 MB

  rpe_table_kernel<<<16, 256, 0, stream>>>(cpb_w1, cpb_b1, cpb_w2, table);
  cvt_bf16_kernel<<<512, 256, 0, stream>>>(w_embed, wE, 131072);
  cvt_bf16_kernel<<<96, 256, 0, stream>>>(w_qkv, wQ, 24576);
  cvt_bf16_kernel<<<32, 256, 0, stream>>>(w_proj, wP, 8192);
  transpose_cvt_kernel<<<dim3(128, 8), 256, 0, stream>>>(w_unembed, wUt);
  im2col_bf16_kernel<<<8192, 256, 0, stream>>>(x, Abig);

  // embed: tok[8192,256](bf16) = A[8192,4096] @ wE^T + b_embed
  gemm_mfma_kernel<1><<<dim3(2, 64), 256, 0, stream>>>(
      Abig, wE, b_embed, tok, 8192, 256, 4096, 4096, 4096, 256);
  // qkv: [8192,768](fp32) = tok @ wQ^T + b_qkv
  gemm_mfma_kernel<0><<<dim3(6, 64), 256, 0, stream>>>(
      tok, wQ, b_qkv, qkvb, 8192, 768, 256, 256, 256, 768);
  attn_kernel<<<1024, 256, 0, stream>>>(qkvb, table, attno);
  // proj: z2[8192,256](bf16) = attno @ wP^T + b_proj
  gemm_mfma_kernel<1><<<dim3(2, 64), 256, 0, stream>>>(
      attno, wP, b_proj, z2, 8192, 256, 256, 256, 256, 256);
  // unembed + fused col2im: y = (z2 @ wUt^T)[bn][opq] scattered + b_unembed
  gemm_mfma_kernel<2><<<dim3(32, 64), 256, 0, stream>>>(
      z2, wUt, b_unembed, out, 8192, 4096, 256, 256, 256, 0);
}

// Round 3
// 606.550 us; speedup vs baseline: 2.4800x; 1.4052x over previous
//
#include <hip/hip_runtime.h>
#include <cstdint>
#include <cstddef>

// PatchAttention on MI355X — round 3: MFMA flash attention (S^T orientation),
// pre-transposed V from the QKV epilogue, precomputed bf16 RPE bias array.

typedef __bf16 bf16x8 __attribute__((ext_vector_type(8)));
typedef float f32x4 __attribute__((ext_vector_type(4)));
typedef unsigned short u16x4 __attribute__((ext_vector_type(4)));

__device__ __forceinline__ unsigned short f2bf(float f) {
  unsigned u = __builtin_bit_cast(unsigned, f);
  u += 0x7fffu + ((u >> 16) & 1u);  // round-to-nearest-even
  return (unsigned short)(u >> 16);
}
__device__ __forceinline__ float bf2f(unsigned short u) {
  return __builtin_bit_cast(float, ((unsigned)u) << 16);
}

// async 16B global -> LDS (wave-uniform base + lane*16 layout)
__device__ __forceinline__ void async_ld16(const void* g, void* l) {
  __builtin_amdgcn_global_load_lds(
      (const __attribute__((address_space(1))) void*)g,
      (__attribute__((address_space(3))) void*)l, 16, 0, 0);
}

// ---------------------------------------------------------------------------
// RPE table: MLP(2 -> 512 -> 8) over the 63x63 relative-coordinate grid.
__global__ __launch_bounds__(256) void rpe_table_kernel(
    const float* __restrict__ w1, const float* __restrict__ b1,
    const float* __restrict__ w2, float* __restrict__ table) {
  int t = blockIdx.x * 256 + threadIdx.x;
  if (t >= 3969) return;
  int a = t / 63, c = t - a * 63;
  float rh = (float)(a - 31) * (1.0f / 31.0f);
  float rw = (float)(c - 31) * (1.0f / 31.0f);
  float acc[8];
#pragma unroll
  for (int h = 0; h < 8; h++) acc[h] = 0.f;
  for (int j = 0; j < 512; j++) {
    float hv = fmaxf(rh * w1[2 * j] + rw * w1[2 * j + 1] + b1[j], 0.f);
#pragma unroll
    for (int h = 0; h < 8; h++) acc[h] += hv * w2[h * 512 + j];
  }
#pragma unroll
  for (int h = 0; h < 8; h++) table[t * 8 + h] = acc[h];
}

// ---------------------------------------------------------------------------
// Expand table [3969][8] f32 -> biasQK [8 h][1024 q][1024 k] bf16 (16 MB).
__global__ __launch_bounds__(256) void bias_expand_kernel(
    const float* __restrict__ table, unsigned short* __restrict__ biasQK) {
  int t = blockIdx.x * 256 + threadIdx.x;  // 1,048,576 threads, 8 k each
  int k8 = t & 127;
  int q = (t >> 7) & 1023;
  int h = t >> 17;
  int k0 = k8 * 8;
  int qh = q >> 5, qw = q & 31;
  int kh = k0 >> 5, kw0 = k0 & 31;  // kh constant over the 8 k's (aligned)
  int idxbase = (qh - kh + 31) * 63 + (qw - kw0 + 31);
  unsigned short pk[8];
#pragma unroll
  for (int j = 0; j < 8; j++)
    pk[j] = f2bf(table[(size_t)(idxbase - j) * 8 + h]);
  *(uint4*)(biasQK + ((size_t)h << 20) + (size_t)q * 1024 + k0) =
      *(const uint4*)pk;
}

// ---------------------------------------------------------------------------
// generic fp32 -> bf16 convert, 8 elems/thread
__global__ __launch_bounds__(256) void cvt_bf16_kernel(
    const float* __restrict__ src, unsigned short* __restrict__ dst, int n8) {
  int i = blockIdx.x * 256 + threadIdx.x;
  if (i >= n8) return;
  const float4* s4 = (const float4*)src + (size_t)i * 2;
  float4 a = s4[0], b = s4[1];
  unsigned short t[8] = {f2bf(a.x), f2bf(a.y), f2bf(a.z), f2bf(a.w),
                         f2bf(b.x), f2bf(b.y), f2bf(b.z), f2bf(b.w)};
  *(uint4*)(dst + (size_t)i * 8) = *(const uint4*)t;
}

// transpose+convert: src [256][4096] f32 -> dst [4096][256] bf16
__global__ __launch_bounds__(256) void transpose_cvt_kernel(
    const float* __restrict__ src, unsigned short* __restrict__ dst) {
  __shared__ float tile[32][33];
  int bx = blockIdx.x;
  int by = blockIdx.y;
  int tx = threadIdx.x & 31, ty = threadIdx.x >> 5;
#pragma unroll
  for (int r = 0; r < 32; r += 8)
    tile[ty + r][tx] = src[(size_t)(by * 32 + ty + r) * 4096 + bx * 32 + tx];
  __syncthreads();
#pragma unroll
  for (int r = 0; r < 32; r += 8)
    dst[(size_t)(bx * 32 + ty + r) * 256 + by * 32 + tx] = f2bf(tile[tx][ty + r]);
}

// ---------------------------------------------------------------------------
// im2col: x [8,256,128,128] f32 -> A [8192, 4096=(c,p,q)] bf16
__global__ __launch_bounds__(256) void im2col_bf16_kernel(
    const float* __restrict__ x, unsigned short* __restrict__ A) {
  int gid = blockIdx.x * 256 + threadIdx.x;
  int bn = gid & 8191;
  int c = gid >> 13;
  int b = bn >> 10;
  int hw = bn & 1023;
  int h = hw >> 5, w = hw & 31;
  const float4* x4 = (const float4*)x;
  int base = ((b * 256 + c) * 128 + 4 * h) * 32 + w;
  unsigned short t[16];
#pragma unroll
  for (int p = 0; p < 4; p++) {
    float4 v = x4[base + p * 32];
    t[p * 4 + 0] = f2bf(v.x); t[p * 4 + 1] = f2bf(v.y);
    t[p * 4 + 2] = f2bf(v.z); t[p * 4 + 3] = f2bf(v.w);
  }
  unsigned short* dst = A + (size_t)bn * 4096 + c * 16;
  *(uint4*)dst = *(const uint4*)t;
  *(uint4*)(dst + 8) = *(const uint4*)(t + 8);
}

// ---------------------------------------------------------------------------
// bf16 MFMA GEMM: C[M,N] = A[M,K] * B^T (B given [N,K] bf16) + bias.
// CMODE: 1 = bf16 C, 2 = fused col2im into y[8,256,128,128] f32,
//        3 = fused QKV split: Q,K -> [bh][n][32] bf16 (Q scaled), V -> V^T
//            [bh][32][1024] bf16; Cv points at the 3-section base.
template <int CMODE>
__global__ __launch_bounds__(256) void gemm_mfma_kernel(
    const unsigned short* __restrict__ A, const unsigned short* __restrict__ B,
    const float* __restrict__ bias, void* __restrict__ Cv,
    int M, int N, int K, int lda, int ldb, int ldc) {
  __shared__ unsigned short As[128 * 32];
  __shared__ unsigned short Bs[128 * 32];
  int tid = threadIdx.x;
  int lane = tid & 63;
  int wave = tid >> 6;
  int m0 = blockIdx.y * 128, n0 = blockIdx.x * 128;
  int wm = (wave & 1) * 64, wn = (wave >> 1) * 64;

  f32x4 acc[4][4];
#pragma unroll
  for (int i = 0; i < 4; i++)
#pragma unroll
    for (int j = 0; j < 4; j++) acc[i][j] = (f32x4){0.f, 0.f, 0.f, 0.f};

  int f0 = tid, f1 = tid + 256;
  const unsigned short* Ag0 = A + (size_t)(m0 + (f0 >> 2)) * lda + (f0 & 3) * 8;
  const unsigned short* Ag1 = A + (size_t)(m0 + (f1 >> 2)) * lda + (f1 & 3) * 8;
  const unsigned short* Bg0 = B + (size_t)(n0 + (f0 >> 2)) * ldb + (f0 & 3) * 8;
  const unsigned short* Bg1 = B + (size_t)(n0 + (f1 >> 2)) * ldb + (f1 & 3) * 8;
  unsigned short* Al0 = As + f0 * 8;
  unsigned short* Al1 = As + f1 * 8;
  unsigned short* Bl0 = Bs + f0 * 8;
  unsigned short* Bl1 = Bs + f1 * 8;

  int fr = lane & 15;
  int fh = lane >> 4;

  for (int k0 = 0; k0 < K; k0 += 32) {
    __syncthreads();
    async_ld16(Ag0 + k0, Al0);
    async_ld16(Ag1 + k0, Al1);
    async_ld16(Bg0 + k0, Bl0);
    async_ld16(Bg1 + k0, Bl1);
    __syncthreads();

    bf16x8 af[4], bf[4];
#pragma unroll
    for (int t = 0; t < 4; t++) {
      af[t] = *(const bf16x8*)(As + (wm + t * 16 + fr) * 32 + fh * 8);
      bf[t] = *(const bf16x8*)(Bs + (wn + t * 16 + fr) * 32 + fh * 8);
    }
#pragma unroll
    for (int mt = 0; mt < 4; mt++)
#pragma unroll
      for (int nt = 0; nt < 4; nt++)
        acc[mt][nt] = __builtin_amdgcn_mfma_f32_16x16x32_bf16(
            af[mt], bf[nt], acc[mt][nt], 0, 0, 0);
  }

  // epilogue: C/D layout col = lane&15, row = (lane>>4)*4 + reg
#pragma unroll
  for (int mt = 0; mt < 4; mt++) {
    int row0 = m0 + wm + mt * 16 + fh * 4;
    if (CMODE == 2) {
      int b = row0 >> 10, hp = (row0 >> 5) & 31, wp = row0 & 31;
      size_t rowoff0 = (size_t)b * 4194304 + hp * 512 + wp * 4;
      float* y = (float*)Cv;
#pragma unroll
      for (int nt = 0; nt < 4; nt++) {
        int col = n0 + wn + nt * 16 + fr;
        int o = col >> 4, p = (col >> 2) & 3, q = col & 3;
        size_t coloff = (size_t)o * 16384 + p * 128 + q;
        float bv = bias[o];
#pragma unroll
        for (int r = 0; r < 4; r++)
          y[rowoff0 + r * 4 + coloff] = acc[mt][nt][r] + bv;
      }
    } else if (CMODE == 3) {
      unsigned short* base = (unsigned short*)Cv;
#pragma unroll
      for (int nt = 0; nt < 4; nt++) {
        int col = n0 + wn + nt * 16 + fr;
        int which = col >> 8, hh = (col >> 5) & 7, d = col & 31;
        float bv = bias[col];
#pragma unroll
        for (int r = 0; r < 4; r++) {
          int row = row0 + r;
          int bb = row >> 10, nn = row & 1023;
          int bh = bb * 8 + hh;
          float v = acc[mt][nt][r] + bv;
          if (which == 0) v *= 0.17677669529663687f;  // 1/sqrt(32)
          size_t addr;
          if (which < 2)
            addr = (size_t)which * 2097152 + ((size_t)bh * 1024 + nn) * 32 + d;
          else
            addr = (size_t)2 * 2097152 + (size_t)bh * 32768 + (size_t)d * 1024 + nn;
          base[addr] = f2bf(v);
        }
      }
    } else {
#pragma unroll
      for (int nt = 0; nt < 4; nt++) {
        int col = n0 + wn + nt * 16 + fr;
        float bv = bias ? bias[col] : 0.f;
        unsigned short* C = (unsigned short*)Cv;
#pragma unroll
        for (int r = 0; r < 4; r++)
          C[(size_t)(row0 + r) * ldc + col] = f2bf(acc[mt][nt][r] + bv);
      }
    }
  }
}

// ---------------------------------------------------------------------------
// MFMA flash attention. Block = (h, b, 128-q tile), 256 threads (4 waves,
// 32 q each). S^T = K·Q^T per 64-k step; C-layout gives lane fixed q
// (=lane&15) and 4 consecutive k per reg -> P stored [q][k] with b64 writes,
// read back as B-frags with b128; V^T staged [d][k] for A-frags. O^T
// accumulates in C-layout (q=lane&15) so softmax rescale is in-register.
__global__ __launch_bounds__(256) void attn_mfma_kernel(
    const unsigned short* __restrict__ Qb, const unsigned short* __restrict__ Kb,
    const unsigned short* __restrict__ Vtb,
    const unsigned short* __restrict__ biasQK,
    unsigned short* __restrict__ out) {
  __shared__ unsigned short sm[21888];  // 43.8 KB
  unsigned short* Ks = sm;              // [64][36]
  unsigned short* Vt = sm + 2304;       // [32][68]
  unsigned short* Bsh = sm + 4480;      // [128][68]
  unsigned short* Qs = sm + 13184;      // [128][36]  (overlaps Ps; Q read once)
  unsigned short* Ps = sm + 13184;      // 4 x [32][68] per-wave

  int tid = threadIdx.x;
  int lane = tid & 63, w = tid >> 6;
  int n = lane & 15, g = lane >> 4;
  int blk = blockIdx.x;
  int qt = blk & 7, b = (blk >> 3) & 7, h = blk >> 6;
  int bh = b * 8 + h;
  int q0 = qt * 128;

  const unsigned short* Qg = Qb + ((size_t)bh * 1024 + q0) * 32;
  const unsigned short* Kg = Kb + (size_t)bh * 1024 * 32;
  const unsigned short* Vg = Vtb + (size_t)bh * 32 * 1024;
  const unsigned short* Bg = biasQK + ((size_t)h << 20) + (size_t)q0 * 1024;

  // stage Q [128][32] -> Qs [128][36]
#pragma unroll
  for (int i = 0; i < 2; i++) {
    int idx = i * 256 + tid;
    int r = idx >> 2, c = idx & 3;
    *(uint4*)(Qs + r * 36 + c * 8) = *(const uint4*)(Qg + (size_t)r * 32 + c * 8);
  }
  __syncthreads();
  bf16x8 qf[2];
  qf[0] = *(const bf16x8*)(Qs + (w * 32 + n) * 36 + g * 8);
  qf[1] = *(const bf16x8*)(Qs + (w * 32 + 16 + n) * 36 + g * 8);

  f32x4 oacc[2][2];  // [dt][nt], O^T[d][q]
#pragma unroll
  for (int i = 0; i < 2; i++)
#pragma unroll
    for (int j = 0; j < 2; j++) oacc[i][j] = (f32x4){0.f, 0.f, 0.f, 0.f};
  float m_run[2] = {-1e30f, -1e30f}, l_run[2] = {0.f, 0.f};

  unsigned short* Pw = Ps + w * 2176;

  for (int ks = 0; ks < 16; ks++) {
    int k0 = ks * 64;
    __syncthreads();  // prior compute done (also fences Qs reads on ks==0)
    {  // stage K tile [64][32] -> [64][36]
      int r = tid >> 2, c = tid & 3;
      *(uint4*)(Ks + r * 36 + c * 8) =
          *(const uint4*)(Kg + (size_t)(k0 + r) * 32 + c * 8);
    }
    {  // stage V^T tile [32][64] -> [32][68]
      int d = tid >> 3, c = tid & 7;
      *(uint4*)(Vt + d * 68 + c * 8) =
          *(const uint4*)(Vg + (size_t)d * 1024 + k0 + c * 8);
    }
#pragma unroll
    for (int i = 0; i < 4; i++) {  // stage bias tile [128][64] -> [128][68]
      int idx = i * 256 + tid;
      int r = idx >> 3, c = idx & 7;
      *(uint4*)(Bsh + r * 68 + c * 8) =
          *(const uint4*)(Bg + (size_t)r * 1024 + k0 + c * 8);
    }
    __syncthreads();

    // S^T[k][q]: A = K rows, B = Q rows
    bf16x8 kf[4];
#pragma unroll
    for (int mt = 0; mt < 4; mt++)
      kf[mt] = *(const bf16x8*)(Ks + (mt * 16 + n) * 36 + g * 8);
    f32x4 s[4][2];
#pragma unroll
    for (int mt = 0; mt < 4; mt++)
#pragma unroll
      for (int nt = 0; nt < 2; nt++)
        s[mt][nt] = __builtin_amdgcn_mfma_f32_16x16x32_bf16(
            kf[mt], qf[nt], (f32x4){0.f, 0.f, 0.f, 0.f}, 0, 0, 0);

    // + bias (lane q = w*32+nt*16+n, k = mt*16+g*4+r)
#pragma unroll
    for (int mt = 0; mt < 4; mt++)
#pragma unroll
      for (int nt = 0; nt < 2; nt++) {
        u16x4 bb = *(const u16x4*)(Bsh + (w * 32 + nt * 16 + n) * 68 +
                                   mt * 16 + g * 4);
#pragma unroll
        for (int r = 0; r < 4; r++) s[mt][nt][r] += bf2f(bb[r]);
      }

    // online softmax per q (reduce over regs + lane groups via xor 16/32)
    float alpha[2];
#pragma unroll
    for (int nt = 0; nt < 2; nt++) {
      float mx = -1e30f;
#pragma unroll
      for (int mt = 0; mt < 4; mt++)
#pragma unroll
        for (int r = 0; r < 4; r++) mx = fmaxf(mx, s[mt][nt][r]);
      mx = fmaxf(mx, __shfl_xor(mx, 16, 64));
      mx = fmaxf(mx, __shfl_xor(mx, 32, 64));
      float m_new = fmaxf(m_run[nt], mx);
      alpha[nt] = __expf(m_run[nt] - m_new);
      m_run[nt] = m_new;
      float ls = 0.f;
#pragma unroll
      for (int mt = 0; mt < 4; mt++) {
#pragma unroll
        for (int r = 0; r < 4; r++) {
          float p = __expf(s[mt][nt][r] - m_new);
          s[mt][nt][r] = p;
          ls += p;
        }
        u16x4 pk = {f2bf(s[mt][nt][0]), f2bf(s[mt][nt][1]),
                    f2bf(s[mt][nt][2]), f2bf(s[mt][nt][3])};
        *(u16x4*)(Pw + (nt * 16 + n) * 68 + mt * 16 + g * 4) = pk;
      }
      ls += __shfl_xor(ls, 16, 64);
      ls += __shfl_xor(ls, 32, 64);
      l_run[nt] = l_run[nt] * alpha[nt] + ls;
    }

    // O^T += V^T · P^T   (same-wave LDS RAW on Pw: compiler inserts lgkmcnt)
#pragma unroll
    for (int dt = 0; dt < 2; dt++)
#pragma unroll
      for (int nt = 0; nt < 2; nt++)
#pragma unroll
        for (int r = 0; r < 4; r++) oacc[dt][nt][r] *= alpha[nt];
#pragma unroll
    for (int kt = 0; kt < 2; kt++) {
      bf16x8 vf[2], pf[2];
#pragma unroll
      for (int dt = 0; dt < 2; dt++)
        vf[dt] = *(const bf16x8*)(Vt + (dt * 16 + n) * 68 + kt * 32 + g * 8);
#pragma unroll
      for (int nt = 0; nt < 2; nt++)
        pf[nt] = *(const bf16x8*)(Pw + (nt * 16 + n) * 68 + kt * 32 + g * 8);
#pragma unroll
      for (int dt = 0; dt < 2; dt++)
#pragma unroll
        for (int nt = 0; nt < 2; nt++)
          oacc[dt][nt] = __builtin_amdgcn_mfma_f32_16x16x32_bf16(
              vf[dt], pf[nt], oacc[dt][nt], 0, 0, 0);
    }
  }

  // epilogue: O^T C-layout -> out[token][256] bf16
  float inv[2] = {1.f / l_run[0], 1.f / l_run[1]};
#pragma unroll
  for (int dt = 0; dt < 2; dt++)
#pragma unroll
    for (int nt = 0; nt < 2; nt++)
#pragma unroll
      for (int r = 0; r < 4; r++) {
        int d = dt * 16 + g * 4 + r;
        int q = q0 + w * 32 + nt * 16 + n;
        out[(size_t)(b * 1024 + q) * 256 + h * 32 + d] =
            f2bf(oacc[dt][nt][r] * inv[nt]);
      }
}

// ---------------------------------------------------------------------------
extern "C" void kernel_launch(void* const* d_in, const int* in_sizes, int n_in,
                              void* d_out, int out_size, void* d_ws, size_t ws_size,
                              hipStream_t stream) {
  const float* x         = (const float*)d_in[0];
  const float* w_embed   = (const float*)d_in[1];
  const float* b_embed   = (const float*)d_in[2];
  const float* cpb_w1    = (const float*)d_in[3];
  const float* cpb_b1    = (const float*)d_in[4];
  const float* cpb_w2    = (const float*)d_in[5];
  const float* w_qkv     = (const float*)d_in[6];
  const float* b_qkv     = (const float*)d_in[7];
  const float* w_proj    = (const float*)d_in[8];
  const float* b_proj    = (const float*)d_in[9];
  const float* w_unembed = (const float*)d_in[10];
  const float* b_unembed = (const float*)d_in[11];
  float* out = (float*)d_out;

  // workspace layout (~105 MB)
  char* w = (char*)d_ws;
  unsigned short* Abig  = (unsigned short*)w; w += (size_t)8192 * 4096 * 2;  // 64 MB
  unsigned short* tok   = (unsigned short*)w; w += (size_t)8192 * 256 * 2;   //  4 MB
  unsigned short* qkvB  = (unsigned short*)w; w += (size_t)3 * 2097152 * 2;  // 12 MB
  unsigned short* attno = (unsigned short*)w; w += (size_t)8192 * 256 * 2;   //  4 MB
  unsigned short* z2    = (unsigned short*)w; w += (size_t)8192 * 256 * 2;   //  4 MB
  float*          table = (float*)w;          w += (size_t)32768 * 4;        // 128 KB
  unsigned short* biasQ = (unsigned short*)w; w += (size_t)8388608 * 2;      // 16 MB
  unsigned short* wE    = (unsigned short*)w; w += (size_t)1048576 * 2;      //  2 MB
  unsigned short* wQ    = (unsigned short*)w; w += (size_t)196608 * 2;       // 384 KB
  unsigned short* wP    = (unsigned short*)w; w += (size_t)65536 * 2;        // 128 KB
  unsigned short* wUt   = (unsigned short*)w; w += (size_t)1048576 * 2;      //  2 MB

  unsigned short* Qb  = qkvB;
  unsigned short* Kb  = qkvB + 2097152;
  unsigned short* Vtb = qkvB + 2 * 2097152;

  rpe_table_kernel<<<16, 256, 0, stream>>>(cpb_w1, cpb_b1, cpb_w2, table);
  bias_expand_kernel<<<4096, 256, 0, stream>>>(table, biasQ);
  cvt_bf16_kernel<<<512, 256, 0, stream>>>(w_embed, wE, 131072);
  cvt_bf16_kernel<<<96, 256, 0, stream>>>(w_qkv, wQ, 24576);
  cvt_bf16_kernel<<<32, 256, 0, stream>>>(w_proj, wP, 8192);
  transpose_cvt_kernel<<<dim3(128, 8), 256, 0, stream>>>(w_unembed, wUt);
  im2col_bf16_kernel<<<8192, 256, 0, stream>>>(x, Abig);

  // embed: tok[8192,256](bf16) = A[8192,4096] @ wE^T + b_embed
  gemm_mfma_kernel<1><<<dim3(2, 64), 256, 0, stream>>>(
      Abig, wE, b_embed, tok, 8192, 256, 4096, 4096, 4096, 256);
  // qkv + fused split/scale/transpose into Qb/Kb/Vtb
  gemm_mfma_kernel<3><<<dim3(6, 64), 256, 0, stream>>>(
      tok, wQ, b_qkv, qkvB, 8192, 768, 256, 256, 256, 0);
  attn_mfma_kernel<<<512, 256, 0, stream>>>(Qb, Kb, Vtb, biasQ, attno);
  // proj: z2[8192,256](bf16) = attno @ wP^T + b_proj
  gemm_mfma_kernel<1><<<dim3(2, 64), 256, 0, stream>>>(
      attno, wP, b_proj, z2, 8192, 256, 256, 256, 256, 256);
  // unembed + fused col2im
  gemm_mfma_kernel<2><<<dim3(32, 64), 256, 0, stream>>>(
      z2, wUt, b_unembed, out, 8192, 4096, 256, 256, 256, 0);
}